// Round 17
// baseline (205.962 us; speedup 1.0000x reference)
//
#include <hip/hip_runtime.h>
#include <math.h>

#define NB 46
#define NS 50
#define ND 768
#define GAMA 0.96875f
#define NM 2300   // NB*NS rows

using bfrag  = __attribute__((ext_vector_type(8))) short;   // 8 bf16 = 4 VGPRs
using f32x16 = __attribute__((ext_vector_type(16))) float;  // 32x32 acc

union FragU { unsigned u[4]; bfrag f; };

// hi/lo bf16 split of 8 f32 (truncation; combined ~16-bit mantissa)
__device__ __forceinline__ void cvt_hilo(const float f[8], bfrag& fh, bfrag& fl)
{
    FragU uh, ul;
    #pragma unroll
    for (int t = 0; t < 4; t++) {
        const unsigned b0 = __float_as_uint(f[2 * t]);
        const unsigned b1 = __float_as_uint(f[2 * t + 1]);
        uh.u[t] = (b0 >> 16) | (b1 & 0xFFFF0000u);
        const float r0 = f[2 * t]     - __uint_as_float(b0 & 0xFFFF0000u);
        const float r1 = f[2 * t + 1] - __uint_as_float(b1 & 0xFFFF0000u);
        ul.u[t] = (__float_as_uint(r0) >> 16) | (__float_as_uint(r1) & 0xFFFF0000u);
    }
    fh = uh.f; fl = ul.f;
}

// ---------------- Kernel 1: QKV projections via MFMA + LDS staging --------
// (R16 version, unchanged — coalesced staging fixed the overfetch, -82us.)
__global__ __launch_bounds__(256) void qkv_gemm(
    const float* __restrict__ text_emb, const float* __restrict__ emb,
    const float* __restrict__ Wq, const float* __restrict__ bq,
    const float* __restrict__ Wk, const float* __restrict__ bk,
    const float* __restrict__ Wv, const float* __restrict__ bv,
    float* __restrict__ Q, float* __restrict__ K, float* __restrict__ V)
{
    const int z = blockIdx.z;
    const float* X    = (z == 0) ? text_emb : emb;
    const float* W    = (z == 0) ? Wq : (z == 1) ? Wk : Wv;
    const float* bias = (z == 0) ? bq : (z == 1) ? bk : bv;
    float* out        = (z == 0) ? Q  : (z == 1) ? K  : V;

    __shared__ float Xs[32][68];
    __shared__ float Ws[32][68];

    const int tid = threadIdx.x;
    const int w   = tid >> 6;           // wave 0..3
    const int l   = tid & 63;
    const int c   = l & 31;
    const int h   = l >> 5;
    const int wm  = w >> 1, wn = w & 1; // quadrant
    const int m0  = blockIdx.x * 64, n0 = blockIdx.y * 64;

    const int lrow = tid >> 2;          // 0..63
    const int lk   = (tid & 3) * 4;     // 0,4,8,12
    const int xm   = m0 + lrow;
    const float* __restrict__ Xrow = X + (size_t)(xm < NM ? xm : 0) * ND;
    const float* __restrict__ Wrow = W + (size_t)(n0 + lrow) * ND;

    f32x16 acc;
    #pragma unroll
    for (int g = 0; g < 16; g++) acc[g] = 0.f;

    for (int k0 = 0; k0 < ND; k0 += 32) {
        const float4 xv0 = *reinterpret_cast<const float4*>(&Xrow[k0 + lk]);
        const float4 xv1 = *reinterpret_cast<const float4*>(&Xrow[k0 + 16 + lk]);
        const float4 wv0 = *reinterpret_cast<const float4*>(&Wrow[k0 + lk]);
        const float4 wv1 = *reinterpret_cast<const float4*>(&Wrow[k0 + 16 + lk]);
        __syncthreads();
        Xs[lk + 0][lrow] = xv0.x; Xs[lk + 1][lrow] = xv0.y;
        Xs[lk + 2][lrow] = xv0.z; Xs[lk + 3][lrow] = xv0.w;
        Xs[16 + lk + 0][lrow] = xv1.x; Xs[16 + lk + 1][lrow] = xv1.y;
        Xs[16 + lk + 2][lrow] = xv1.z; Xs[16 + lk + 3][lrow] = xv1.w;
        Ws[lk + 0][lrow] = wv0.x; Ws[lk + 1][lrow] = wv0.y;
        Ws[lk + 2][lrow] = wv0.z; Ws[lk + 3][lrow] = wv0.w;
        Ws[16 + lk + 0][lrow] = wv1.x; Ws[16 + lk + 1][lrow] = wv1.y;
        Ws[16 + lk + 2][lrow] = wv1.z; Ws[16 + lk + 3][lrow] = wv1.w;
        __syncthreads();

        #pragma unroll
        for (int kt = 0; kt < 2; kt++) {
            float fx[8], fw[8];
            #pragma unroll
            for (int j = 0; j < 8; j++) {
                fx[j] = Xs[16 * kt + 8 * h + j][32 * wm + c];
                fw[j] = Ws[16 * kt + 8 * h + j][32 * wn + c];
            }
            bfrag Ah, Al, Bh, Bl;
            cvt_hilo(fx, Ah, Al);
            cvt_hilo(fw, Bh, Bl);
            acc = __builtin_amdgcn_mfma_f32_32x32x16_bf16(Ah, Bh, acc, 0, 0, 0);
            acc = __builtin_amdgcn_mfma_f32_32x32x16_bf16(Ah, Bl, acc, 0, 0, 0);
            acc = __builtin_amdgcn_mfma_f32_32x32x16_bf16(Al, Bh, acc, 0, 0, 0);
        }
    }

    const float C2 = -0.0239861701969175f; // -2*ln(10000)/768
    const int n = n0 + 32 * wn + c;
    #pragma unroll
    for (int g = 0; g < 16; g++) {
        const int rr = (g & 3) + 8 * (g >> 2) + 4 * h;
        const int m  = m0 + 32 * wm + rr;
        if (m >= NM) continue;
        float v = acc[g] + bias[n];
        if (z < 2) {
            const int bpos = m / NS;  // pe indexed by BATCH position (faithful)
            const float ang = (float)bpos * expf((float)(n >> 1) * C2);
            v += (n & 1) ? cosf(ang) : sinf(ang);
        }
        out[(size_t)m * ND + n] = v;
    }
}

// ---------------- Kernel 2: attention via MFMA, one block per b ------------
// (R15 version, unchanged.)
__global__ __launch_bounds__(256, 1) void attn(
    const float* __restrict__ Q, const float* __restrict__ K,
    const float* __restrict__ V,
    const float* __restrict__ lin_w, const float* __restrict__ lin_b,
    float* __restrict__ Ag, float* __restrict__ ctx_out)
{
    const int b   = blockIdx.x;
    const int tid = threadIdx.x;
    const int w   = tid >> 6;          // wave 0..3
    const int l   = tid & 63;
    const int c   = l & 31;
    const int h   = l >> 5;

    __shared__ float Lsh[9 * 64 * 68];           // 153 KB
    float* SP = Lsh;                              // 4 partial S tiles
    float* QP = Lsh + 4 * 64 * 68;                // 4 partial Qt tiles
    float* Pf = Lsh + 8 * 64 * 68;                // P

    const float* __restrict__ Qb = Q + (size_t)b * NS * ND;
    const float* __restrict__ Kb = K + (size_t)b * NS * ND;
    const float* __restrict__ Vb = V + (size_t)b * NS * ND;

    f32x16 accS[2][2], accQ[2][2];
    #pragma unroll
    for (int mt = 0; mt < 2; mt++)
        #pragma unroll
        for (int nt = 0; nt < 2; nt++)
            #pragma unroll
            for (int g = 0; g < 16; g++) { accS[mt][nt][g] = 0.f; accQ[mt][nt][g] = 0.f; }

    const int ks = w * 192;
    for (int kt = 0; kt < 12; ++kt) {
        const int ko = ks + kt * 16 + 8 * h;
        bfrag Qh[2], Ql[2], Kh[2], Kl[2], Wh[2], Wl[2];
        #pragma unroll
        for (int mt = 0; mt < 2; mt++) {
            const int row = 32 * mt + c;
            const int r = (row < NS) ? row : 0;
            float f[8];
            {
                const float4 a0 = *reinterpret_cast<const float4*>(&Qb[(size_t)r * ND + ko]);
                const float4 a1 = *reinterpret_cast<const float4*>(&Qb[(size_t)r * ND + ko + 4]);
                f[0]=a0.x; f[1]=a0.y; f[2]=a0.z; f[3]=a0.w; f[4]=a1.x; f[5]=a1.y; f[6]=a1.z; f[7]=a1.w;
            }
            cvt_hilo(f, Qh[mt], Ql[mt]);
            {
                const float4 a0 = *reinterpret_cast<const float4*>(&Kb[(size_t)r * ND + ko]);
                const float4 a1 = *reinterpret_cast<const float4*>(&Kb[(size_t)r * ND + ko + 4]);
                f[0]=a0.x; f[1]=a0.y; f[2]=a0.z; f[3]=a0.w; f[4]=a1.x; f[5]=a1.y; f[6]=a1.z; f[7]=a1.w;
            }
            cvt_hilo(f, Kh[mt], Kl[mt]);
            {
                const float4 a0 = *reinterpret_cast<const float4*>(&lin_w[(size_t)r * ND + ko]);
                const float4 a1 = *reinterpret_cast<const float4*>(&lin_w[(size_t)r * ND + ko + 4]);
                f[0]=a0.x; f[1]=a0.y; f[2]=a0.z; f[3]=a0.w; f[4]=a1.x; f[5]=a1.y; f[6]=a1.z; f[7]=a1.w;
            }
            cvt_hilo(f, Wh[mt], Wl[mt]);
        }
        #pragma unroll
        for (int mt = 0; mt < 2; mt++)
            #pragma unroll
            for (int nt = 0; nt < 2; nt++) {
                f32x16 a = accS[mt][nt];
                a = __builtin_amdgcn_mfma_f32_32x32x16_bf16(Qh[mt], Kh[nt], a, 0, 0, 0);
                a = __builtin_amdgcn_mfma_f32_32x32x16_bf16(Qh[mt], Kl[nt], a, 0, 0, 0);
                a = __builtin_amdgcn_mfma_f32_32x32x16_bf16(Ql[mt], Kh[nt], a, 0, 0, 0);
                accS[mt][nt] = a;
                f32x16 q = accQ[mt][nt];
                q = __builtin_amdgcn_mfma_f32_32x32x16_bf16(Qh[mt], Wh[nt], q, 0, 0, 0);
                q = __builtin_amdgcn_mfma_f32_32x32x16_bf16(Qh[mt], Wl[nt], q, 0, 0, 0);
                q = __builtin_amdgcn_mfma_f32_32x32x16_bf16(Ql[mt], Wh[nt], q, 0, 0, 0);
                accQ[mt][nt] = q;
            }
    }

    {
        float* SPw = SP + w * (64 * 68);
        float* QPw = QP + w * (64 * 68);
        #pragma unroll
        for (int mt = 0; mt < 2; mt++)
            #pragma unroll
            for (int nt = 0; nt < 2; nt++)
                #pragma unroll
                for (int g = 0; g < 16; g++) {
                    const int rg  = 32 * mt + (g & 3) + 8 * (g >> 2) + 4 * h;
                    const int col = 32 * nt + c;
                    SPw[rg * 68 + col] = accS[mt][nt][g];
                    QPw[rg * 68 + col] = accQ[mt][nt][g];
                }
    }
    __syncthreads();

    {
        const int r  = tid >> 2;
        const int cg = (tid & 3) * 16;
        #pragma unroll
        for (int q4 = 0; q4 < 4; ++q4) {
            const int off = r * 68 + cg + q4 * 4;
            float4 s0 = *reinterpret_cast<const float4*>(&SP[off]);
            float4 s1 = *reinterpret_cast<const float4*>(&SP[64 * 68 + off]);
            float4 s2 = *reinterpret_cast<const float4*>(&SP[2 * 64 * 68 + off]);
            float4 s3 = *reinterpret_cast<const float4*>(&SP[3 * 64 * 68 + off]);
            float4 r4;
            r4.x = 8.f * ((s0.x + s1.x) + (s2.x + s3.x));
            r4.y = 8.f * ((s0.y + s1.y) + (s2.y + s3.y));
            r4.z = 8.f * ((s0.z + s1.z) + (s2.z + s3.z));
            r4.w = 8.f * ((s0.w + s1.w) + (s2.w + s3.w));
            *reinterpret_cast<float4*>(&SP[off]) = r4;
            float4 t0 = *reinterpret_cast<const float4*>(&QP[off]);
            float4 t1 = *reinterpret_cast<const float4*>(&QP[64 * 68 + off]);
            float4 t2 = *reinterpret_cast<const float4*>(&QP[2 * 64 * 68 + off]);
            float4 t3 = *reinterpret_cast<const float4*>(&QP[3 * 64 * 68 + off]);
            float4 u4;
            u4.x = (t0.x + t1.x) + (t2.x + t3.x);
            u4.y = (t0.y + t1.y) + (t2.y + t3.y);
            u4.z = (t0.z + t1.z) + (t2.z + t3.z);
            u4.w = (t0.w + t1.w) + (t2.w + t3.w);
            *reinterpret_cast<float4*>(&QP[off]) = u4;
        }
    }
    __syncthreads();

    if (tid < NS) {
        const float* Sr = SP + tid * 68;
        float mx = -INFINITY;
        for (int c2 = 0; c2 < NS; ++c2) mx = fmaxf(mx, Sr[c2]);
        float sum = 0.f;
        for (int c2 = 0; c2 < NS; ++c2) {
            const float e = expf(Sr[c2] - mx);
            Pf[tid * 68 + c2] = e;
            sum += e;
        }
        const float inv = 1.f / sum;
        for (int c2 = 0; c2 < NS; ++c2) Pf[tid * 68 + c2] *= inv;
        for (int c2 = NS; c2 < 64; ++c2) Pf[tid * 68 + c2] = 0.f;
    }
    for (int e = tid; e < NS * NS; e += 256) {
        const int r = e / NS, cc = e - r * NS;
        Ag[b * (NS * NS) + e] = GAMA * (QP[r * 68 + cc] + lin_b[cc]);
    }
    __syncthreads();

    bfrag Ph[2][4], Pl[2][4];
    #pragma unroll
    for (int mt = 0; mt < 2; mt++)
        #pragma unroll
        for (int kt = 0; kt < 4; kt++) {
            float f[8];
            #pragma unroll
            for (int j = 0; j < 8; j++)
                f[j] = Pf[(32 * mt + c) * 68 + kt * 16 + 8 * h + j];
            cvt_hilo(f, Ph[mt][kt], Pl[mt][kt]);
        }

    for (int j3 = 0; j3 < 3; ++j3) {
        const int dbase = (w * 3 + j3) * 64;
        f32x16 accC[2][2];
        #pragma unroll
        for (int mt = 0; mt < 2; mt++)
            #pragma unroll
            for (int nt = 0; nt < 2; nt++)
                #pragma unroll
                for (int g = 0; g < 16; g++) accC[mt][nt][g] = 0.f;

        #pragma unroll
        for (int nt = 0; nt < 2; nt++) {
            const int d = dbase + 32 * nt + c;
            #pragma unroll
            for (int kt = 0; kt < 4; kt++) {
                float f[8];
                #pragma unroll
                for (int j = 0; j < 8; j++) {
                    const int k2 = kt * 16 + 8 * h + j;
                    f[j] = (k2 < NS) ? Vb[(size_t)k2 * ND + d] : 0.f;
                }
                bfrag Bh, Bl;
                cvt_hilo(f, Bh, Bl);
                #pragma unroll
                for (int mt = 0; mt < 2; mt++) {
                    f32x16 a = accC[mt][nt];
                    a = __builtin_amdgcn_mfma_f32_32x32x16_bf16(Ph[mt][kt], Bh, a, 0, 0, 0);
                    a = __builtin_amdgcn_mfma_f32_32x32x16_bf16(Ph[mt][kt], Bl, a, 0, 0, 0);
                    a = __builtin_amdgcn_mfma_f32_32x32x16_bf16(Pl[mt][kt], Bh, a, 0, 0, 0);
                    accC[mt][nt] = a;
                }
            }
        }
        #pragma unroll
        for (int mt = 0; mt < 2; mt++)
            #pragma unroll
            for (int nt = 0; nt < 2; nt++)
                #pragma unroll
                for (int g = 0; g < 16; g++) {
                    const int rg = 32 * mt + (g & 3) + 8 * (g >> 2) + 4 * h;
                    if (rg < NS)
                        ctx_out[((size_t)b * NS + rg) * ND + dbase + 32 * nt + c] = accC[mt][nt][g];
                }
    }
}

// ---------------- Kernel 3: gamma-decay recurrence via MFMA, 2 waves -------
// R16 analysis: recur (R13) ran at ~105us = 2x its 50us HBM write floor with
// VGPR~160 -> 1 wave/SIMD (A-frags for both row-halves = 64 regs) -> zero
// TLP, every LDS/L2 latency exposed. R17: split the mt dimension across 2
// waves (wave w owns output rows 32w..32w+31): A-frags 32 regs, creg 16 ->
// ~115 total -> __launch_bounds__(128,2) = 2 waves/SIMD, 2x resident waves.
// State Sf is now cross-wave: double-buffered (Sfa/Sfb) so ONE lgkm-only
// barrier per step suffices (write-buf != read-buf removes the read hazard).
// Cx stays wave-local (own-mt rows, program order). Fat-VMEM (R13) and
// load-before-store FIFO order (R7) preserved. MFMA accumulation re-ordered
// per-kt (pure associativity change; error magnitude unchanged).
__device__ __forceinline__ void rec2_step(
    int i, int b, int d0, int c, int h, int wid, int srow, int scol,
    const bfrag (&Ah)[4], const bfrag (&Al)[4],
    float4 (&creg)[4],
    const float* SfR, float* SfW, float* Cx,
    const float* __restrict__ ctx, float* __restrict__ rec)
{
    // [A] flush creg (ctx_i, own-mt rows) -> Cx (wave-local rows)
    #pragma unroll
    for (int it = 0; it < 4; ++it) {
        const int r = (4 * wid + it) * 8 + srow;
        if (r < NS)
            *reinterpret_cast<float4*>(&Cx[r * 32 + scol]) = creg[it];
    }
    // [B] fat loads of ctx_{i+1}, own-mt rows (BEFORE this step's stores)
    if (i + 1 < NB) {
        const float* __restrict__ src = ctx + (size_t)(i + 1) * NS * ND + d0;
        #pragma unroll
        for (int it = 0; it < 4; ++it) {
            const int r = (4 * wid + it) * 8 + srow;
            if (r < NS)
                creg[it] = *reinterpret_cast<const float4*>(&src[(size_t)r * ND + scol]);
        }
    }
    // [C] acc init from Cx (own-mt rows; pad rows exact 0)
    f32x16 acc;
    #pragma unroll
    for (int g = 0; g < 16; g++) {
        const int rg = 32 * wid + (g & 3) + 8 * (g >> 2) + 4 * h;
        acc[g] = Cx[rg * 32 + c];
    }
    // [D]+[E] per kt: B-frags from SfR (full k range, cross-wave: covered by
    // the end-of-previous-step barrier) + 3 MFMAs
    #pragma unroll
    for (int kt = 0; kt < 4; kt++) {
        float f[8];
        #pragma unroll
        for (int j = 0; j < 8; j++)
            f[j] = SfR[(16 * kt + 8 * h + j) * 32 + c];
        bfrag Bh, Bl;
        cvt_hilo(f, Bh, Bl);
        acc = __builtin_amdgcn_mfma_f32_32x32x16_bf16(Ah[kt], Bh, acc, 0, 0, 0);
        acc = __builtin_amdgcn_mfma_f32_32x32x16_bf16(Ah[kt], Bl, acc, 0, 0, 0);
        acc = __builtin_amdgcn_mfma_f32_32x32x16_bf16(Al[kt], Bh, acc, 0, 0, 0);
    }
    // [F] acc -> SfW own-mt rows (pad rows produce exact 0)
    #pragma unroll
    for (int g = 0; g < 16; g++) {
        const int rg = 32 * wid + (g & 3) + 8 * (g >> 2) + 4 * h;
        SfW[rg * 32 + c] = acc[g];
    }
    // [G]+[H] fat read-back of own-mt rows (own wave's writes, DS in-order)
    // + fat stores of rec_i
    float* __restrict__ reci = rec + (size_t)(i * NB + b) * NS * ND + d0;
    #pragma unroll
    for (int it = 0; it < 4; ++it) {
        const int r = (4 * wid + it) * 8 + srow;
        if (r < NS) {
            const float4 v = *reinterpret_cast<const float4*>(&SfW[r * 32 + scol]);
            *reinterpret_cast<float4*>(&reci[(size_t)r * ND + scol]) = v;
        }
    }
    // one LDS-only barrier per step: both waves' SfW visible for next [D]
    asm volatile("s_waitcnt lgkmcnt(0)" ::: "memory");
    __builtin_amdgcn_s_barrier();
    asm volatile("" ::: "memory");
}

__global__ __launch_bounds__(128, 2) void recur(
    const float* __restrict__ Ag, const float* __restrict__ ctx,
    float* __restrict__ rec)
{
    const int blk   = blockIdx.x;          // 0..1103
    const int b     = blk / 24;
    const int chunk = blk - b * 24;        // 0..23 -> 32 cols
    const int tid   = threadIdx.x;
    const int wid   = tid >> 6;            // wave 0,1 = mt half
    const int l     = tid & 63;
    const int c     = l & 31;
    const int h     = l >> 5;
    const int d0    = chunk * 32;
    const int srow  = l >> 3;              // 0..7
    const int scol  = (l & 7) * 4;         // 0,4..28

    __shared__ float Sfa[64 * 32];         // state ping
    __shared__ float Sfb[64 * 32];         // state pong
    __shared__ float Cx [64 * 32];         // ctx staging

    // ---- A fragments (hi/lo), own mt only, ONCE from global ----
    const float* __restrict__ Ab = Ag + b * (NS * NS);
    bfrag Ah[4], Al[4];
    {
        const int row = 32 * wid + c;
        const bool rok = row < NS;
        const float* __restrict__ Arow = Ab + row * NS;
        #pragma unroll
        for (int kt = 0; kt < 4; kt++) {
            FragU uh, ul;
            #pragma unroll
            for (int t = 0; t < 4; t++) {
                const int k0 = 16 * kt + 8 * h + 2 * t;
                const float e = (rok && k0     < NS) ? Arow[k0]     : 0.f;
                const float o = (rok && k0 + 1 < NS) ? Arow[k0 + 1] : 0.f;
                const unsigned ue = __float_as_uint(e), uo = __float_as_uint(o);
                uh.u[t] = (ue >> 16) | (uo & 0xFFFF0000u);
                const float re = e - __uint_as_float(ue & 0xFFFF0000u);
                const float ro = o - __uint_as_float(uo & 0xFFFF0000u);
                ul.u[t] = (__float_as_uint(re) >> 16) | (__float_as_uint(ro) & 0xFFFF0000u);
            }
            Ah[kt] = uh.f; Al[kt] = ul.f;
        }
    }

    // ---- zero pad rows 50..63 of Cx and Sfa (Sfb pads are written as exact
    // zeros by wave1's [F] every step before first read) ----
    for (int idx = tid; idx < 14 * 32; idx += 128) {
        const int rr = 50 + (idx >> 5), cc = idx & 31;
        Cx [rr * 32 + cc] = 0.f;
        Sfa[rr * 32 + cc] = 0.f;
    }

    // ---- step 0: fat load ctx0 (own rows) -> Sfa + rec0; then ctx1 -> creg
    float4 creg[4];
    #pragma unroll
    for (int it = 0; it < 4; ++it) creg[it] = make_float4(0.f, 0.f, 0.f, 0.f);
    {
        const float* __restrict__ src = ctx + d0;
        float4 c0[4];
        #pragma unroll
        for (int it = 0; it < 4; ++it) {
            c0[it] = make_float4(0.f, 0.f, 0.f, 0.f);
            const int r = (4 * wid + it) * 8 + srow;
            if (r < NS)
                c0[it] = *reinterpret_cast<const float4*>(&src[(size_t)r * ND + scol]);
        }
        // prefetch ctx1 before rec0 stores (FIFO discipline)
        const float* __restrict__ s1 = ctx + (size_t)NS * ND + d0;
        #pragma unroll
        for (int it = 0; it < 4; ++it) {
            const int r = (4 * wid + it) * 8 + srow;
            if (r < NS)
                creg[it] = *reinterpret_cast<const float4*>(&s1[(size_t)r * ND + scol]);
        }
        float* __restrict__ r0 = rec + (size_t)b * NS * ND + d0;
        #pragma unroll
        for (int it = 0; it < 4; ++it) {
            const int r = (4 * wid + it) * 8 + srow;
            if (r < NS) {
                *reinterpret_cast<float4*>(&Sfa[r * 32 + scol]) = c0[it];
                *reinterpret_cast<float4*>(&r0[(size_t)r * ND + scol]) = c0[it];
            }
        }
    }
    asm volatile("s_waitcnt lgkmcnt(0)" ::: "memory");
    __builtin_amdgcn_s_barrier();
    asm volatile("" ::: "memory");

    // ---- steps 1..45 (ping-pong; 22 pairs + final odd step) ----
    int i = 1;
    for (; i + 1 < NB; i += 2) {
        rec2_step(i,     b, d0, c, h, wid, srow, scol, Ah, Al, creg, Sfa, Sfb, Cx, ctx, rec);
        rec2_step(i + 1, b, d0, c, h, wid, srow, scol, Ah, Al, creg, Sfb, Sfa, Cx, ctx, rec);
    }
    if (i < NB)
        rec2_step(i, b, d0, c, h, wid, srow, scol, Ah, Al, creg, Sfa, Sfb, Cx, ctx, rec);
}

extern "C" void kernel_launch(void* const* d_in, const int* in_sizes, int n_in,
                              void* d_out, int out_size, void* d_ws, size_t ws_size,
                              hipStream_t stream) {
    const float* text_emb = (const float*)d_in[0];
    const float* emb      = (const float*)d_in[1];
    const float* Wq = (const float*)d_in[2]; const float* bq = (const float*)d_in[3];
    const float* Wk = (const float*)d_in[4]; const float* bk = (const float*)d_in[5];
    const float* Wv = (const float*)d_in[6]; const float* bv = (const float*)d_in[7];
    const float* lw = (const float*)d_in[8]; const float* lb = (const float*)d_in[9];

    float* out = (float*)d_out;
    float* ctx = out;                          // [46,50,768]
    float* rec = out + NB * NS * ND;           // [46,46,50,768]

    float* ws = (float*)d_ws;                  // needs 21.7 MB
    float* Q  = ws;
    float* K  = Q + NB * NS * ND;
    float* V  = K + NB * NS * ND;
    float* Ag = V + NB * NS * ND;              // gamma * Q_trans, [46,50,50]

    qkv_gemm<<<dim3(36, 12, 3), 256, 0, stream>>>(text_emb, emb, Wq, bq, Wk, bk, Wv, bv, Q, K, V);
    attn<<<dim3(NB), 256, 0, stream>>>(Q, K, V, lw, lb, Ag, ctx);
    recur<<<dim3(1104), 128, 0, stream>>>(Ag, ctx, rec);
}

// Round 18
// 196.854 us; speedup vs baseline: 1.0463x; 1.0463x over previous
//
#include <hip/hip_runtime.h>
#include <math.h>

#define NB 46
#define NS 50
#define ND 768
#define GAMA 0.96875f
#define NM 2300   // NB*NS rows

using bfrag  = __attribute__((ext_vector_type(8))) short;   // 8 bf16 = 4 VGPRs
using f32x16 = __attribute__((ext_vector_type(16))) float;  // 32x32 acc

union FragU { unsigned u[4]; bfrag f; };

// hi/lo bf16 split of 8 f32 (truncation; combined ~16-bit mantissa)
__device__ __forceinline__ void cvt_hilo(const float f[8], bfrag& fh, bfrag& fl)
{
    FragU uh, ul;
    #pragma unroll
    for (int t = 0; t < 4; t++) {
        const unsigned b0 = __float_as_uint(f[2 * t]);
        const unsigned b1 = __float_as_uint(f[2 * t + 1]);
        uh.u[t] = (b0 >> 16) | (b1 & 0xFFFF0000u);
        const float r0 = f[2 * t]     - __uint_as_float(b0 & 0xFFFF0000u);
        const float r1 = f[2 * t + 1] - __uint_as_float(b1 & 0xFFFF0000u);
        ul.u[t] = (__float_as_uint(r0) >> 16) | (__float_as_uint(r1) & 0xFFFF0000u);
    }
    fh = uh.f; fl = ul.f;
}

// ---------------- Kernel 1: QKV projections via MFMA + LDS staging --------
// R16 structure (coalesced staging, -82us) + R18: double-buffered LDS tiles
// (one barrier per k-iter instead of two; next-tile loads in flight through
// compute on the current buffer; write-buf != read-buf makes one barrier
// sufficient — same invariant as R5's recur dbuf). Arithmetic identical.
__global__ __launch_bounds__(256) void qkv_gemm(
    const float* __restrict__ text_emb, const float* __restrict__ emb,
    const float* __restrict__ Wq, const float* __restrict__ bq,
    const float* __restrict__ Wk, const float* __restrict__ bk,
    const float* __restrict__ Wv, const float* __restrict__ bv,
    float* __restrict__ Q, float* __restrict__ K, float* __restrict__ V)
{
    const int z = blockIdx.z;
    const float* X    = (z == 0) ? text_emb : emb;
    const float* W    = (z == 0) ? Wq : (z == 1) ? Wk : Wv;
    const float* bias = (z == 0) ? bq : (z == 1) ? bk : bv;
    float* out        = (z == 0) ? Q  : (z == 1) ? K  : V;

    __shared__ float Xs[2][32][68];
    __shared__ float Ws[2][32][68];

    const int tid = threadIdx.x;
    const int w   = tid >> 6;           // wave 0..3
    const int l   = tid & 63;
    const int c   = l & 31;
    const int h   = l >> 5;
    const int wm  = w >> 1, wn = w & 1; // quadrant
    const int m0  = blockIdx.x * 64, n0 = blockIdx.y * 64;

    const int lrow = tid >> 2;          // 0..63
    const int lk   = (tid & 3) * 4;     // 0,4,8,12
    const int xm   = m0 + lrow;
    const float* __restrict__ Xrow = X + (size_t)(xm < NM ? xm : 0) * ND;
    const float* __restrict__ Wrow = W + (size_t)(n0 + lrow) * ND;

    f32x16 acc;
    #pragma unroll
    for (int g = 0; g < 16; g++) acc[g] = 0.f;

    // ---- prologue: stage tile 0 into buffer 0 ----
    {
        const float4 xv0 = *reinterpret_cast<const float4*>(&Xrow[lk]);
        const float4 xv1 = *reinterpret_cast<const float4*>(&Xrow[16 + lk]);
        const float4 wv0 = *reinterpret_cast<const float4*>(&Wrow[lk]);
        const float4 wv1 = *reinterpret_cast<const float4*>(&Wrow[16 + lk]);
        Xs[0][lk + 0][lrow] = xv0.x; Xs[0][lk + 1][lrow] = xv0.y;
        Xs[0][lk + 2][lrow] = xv0.z; Xs[0][lk + 3][lrow] = xv0.w;
        Xs[0][16 + lk + 0][lrow] = xv1.x; Xs[0][16 + lk + 1][lrow] = xv1.y;
        Xs[0][16 + lk + 2][lrow] = xv1.z; Xs[0][16 + lk + 3][lrow] = xv1.w;
        Ws[0][lk + 0][lrow] = wv0.x; Ws[0][lk + 1][lrow] = wv0.y;
        Ws[0][lk + 2][lrow] = wv0.z; Ws[0][lk + 3][lrow] = wv0.w;
        Ws[0][16 + lk + 0][lrow] = wv1.x; Ws[0][16 + lk + 1][lrow] = wv1.y;
        Ws[0][16 + lk + 2][lrow] = wv1.z; Ws[0][16 + lk + 3][lrow] = wv1.w;
        __syncthreads();
    }

    for (int k0 = 0; k0 < ND; k0 += 32) {
        const int  p    = (k0 >> 5) & 1;
        const bool more = (k0 + 32) < ND;

        // issue next-tile loads first (in flight across this tile's compute)
        float4 xv0, xv1, wv0, wv1;
        if (more) {
            xv0 = *reinterpret_cast<const float4*>(&Xrow[k0 + 32 + lk]);
            xv1 = *reinterpret_cast<const float4*>(&Xrow[k0 + 48 + lk]);
            wv0 = *reinterpret_cast<const float4*>(&Wrow[k0 + 32 + lk]);
            wv1 = *reinterpret_cast<const float4*>(&Wrow[k0 + 48 + lk]);
        }

        // compute on buffer p
        #pragma unroll
        for (int kt = 0; kt < 2; kt++) {
            float fx[8], fw[8];
            #pragma unroll
            for (int j = 0; j < 8; j++) {
                fx[j] = Xs[p][16 * kt + 8 * h + j][32 * wm + c];
                fw[j] = Ws[p][16 * kt + 8 * h + j][32 * wn + c];
            }
            bfrag Ah, Al, Bh, Bl;
            cvt_hilo(fx, Ah, Al);
            cvt_hilo(fw, Bh, Bl);
            acc = __builtin_amdgcn_mfma_f32_32x32x16_bf16(Ah, Bh, acc, 0, 0, 0);
            acc = __builtin_amdgcn_mfma_f32_32x32x16_bf16(Ah, Bl, acc, 0, 0, 0);
            acc = __builtin_amdgcn_mfma_f32_32x32x16_bf16(Al, Bh, acc, 0, 0, 0);
        }

        // stage next tile into buffer p^1 (disjoint from all live reads of p)
        if (more) {
            Xs[p ^ 1][lk + 0][lrow] = xv0.x; Xs[p ^ 1][lk + 1][lrow] = xv0.y;
            Xs[p ^ 1][lk + 2][lrow] = xv0.z; Xs[p ^ 1][lk + 3][lrow] = xv0.w;
            Xs[p ^ 1][16 + lk + 0][lrow] = xv1.x; Xs[p ^ 1][16 + lk + 1][lrow] = xv1.y;
            Xs[p ^ 1][16 + lk + 2][lrow] = xv1.z; Xs[p ^ 1][16 + lk + 3][lrow] = xv1.w;
            Ws[p ^ 1][lk + 0][lrow] = wv0.x; Ws[p ^ 1][lk + 1][lrow] = wv0.y;
            Ws[p ^ 1][lk + 2][lrow] = wv0.z; Ws[p ^ 1][lk + 3][lrow] = wv0.w;
            Ws[p ^ 1][16 + lk + 0][lrow] = wv1.x; Ws[p ^ 1][16 + lk + 1][lrow] = wv1.y;
            Ws[p ^ 1][16 + lk + 2][lrow] = wv1.z; Ws[p ^ 1][16 + lk + 3][lrow] = wv1.w;
            __syncthreads();
        }
    }

    // epilogue: C/D layout col=c, row=(g&3)+8*(g>>2)+4*h (R14, verified)
    const float C2 = -0.0239861701969175f; // -2*ln(10000)/768
    const int n = n0 + 32 * wn + c;
    #pragma unroll
    for (int g = 0; g < 16; g++) {
        const int rr = (g & 3) + 8 * (g >> 2) + 4 * h;
        const int m  = m0 + 32 * wm + rr;
        if (m >= NM) continue;
        float v = acc[g] + bias[n];
        if (z < 2) {
            const int bpos = m / NS;  // pe indexed by BATCH position (faithful)
            const float ang = (float)bpos * expf((float)(n >> 1) * C2);
            v += (n & 1) ? cosf(ang) : sinf(ang);
        }
        out[(size_t)m * ND + n] = v;
    }
}

// ---------------- Kernel 2: attention via MFMA, one block per b ------------
// (R15 version, unchanged.)
__global__ __launch_bounds__(256, 1) void attn(
    const float* __restrict__ Q, const float* __restrict__ K,
    const float* __restrict__ V,
    const float* __restrict__ lin_w, const float* __restrict__ lin_b,
    float* __restrict__ Ag, float* __restrict__ ctx_out)
{
    const int b   = blockIdx.x;
    const int tid = threadIdx.x;
    const int w   = tid >> 6;          // wave 0..3
    const int l   = tid & 63;
    const int c   = l & 31;
    const int h   = l >> 5;

    __shared__ float Lsh[9 * 64 * 68];           // 153 KB
    float* SP = Lsh;                              // 4 partial S tiles
    float* QP = Lsh + 4 * 64 * 68;                // 4 partial Qt tiles
    float* Pf = Lsh + 8 * 64 * 68;                // P

    const float* __restrict__ Qb = Q + (size_t)b * NS * ND;
    const float* __restrict__ Kb = K + (size_t)b * NS * ND;
    const float* __restrict__ Vb = V + (size_t)b * NS * ND;

    f32x16 accS[2][2], accQ[2][2];
    #pragma unroll
    for (int mt = 0; mt < 2; mt++)
        #pragma unroll
        for (int nt = 0; nt < 2; nt++)
            #pragma unroll
            for (int g = 0; g < 16; g++) { accS[mt][nt][g] = 0.f; accQ[mt][nt][g] = 0.f; }

    const int ks = w * 192;
    for (int kt = 0; kt < 12; ++kt) {
        const int ko = ks + kt * 16 + 8 * h;
        bfrag Qh[2], Ql[2], Kh[2], Kl[2], Wh[2], Wl[2];
        #pragma unroll
        for (int mt = 0; mt < 2; mt++) {
            const int row = 32 * mt + c;
            const int r = (row < NS) ? row : 0;
            float f[8];
            {
                const float4 a0 = *reinterpret_cast<const float4*>(&Qb[(size_t)r * ND + ko]);
                const float4 a1 = *reinterpret_cast<const float4*>(&Qb[(size_t)r * ND + ko + 4]);
                f[0]=a0.x; f[1]=a0.y; f[2]=a0.z; f[3]=a0.w; f[4]=a1.x; f[5]=a1.y; f[6]=a1.z; f[7]=a1.w;
            }
            cvt_hilo(f, Qh[mt], Ql[mt]);
            {
                const float4 a0 = *reinterpret_cast<const float4*>(&Kb[(size_t)r * ND + ko]);
                const float4 a1 = *reinterpret_cast<const float4*>(&Kb[(size_t)r * ND + ko + 4]);
                f[0]=a0.x; f[1]=a0.y; f[2]=a0.z; f[3]=a0.w; f[4]=a1.x; f[5]=a1.y; f[6]=a1.z; f[7]=a1.w;
            }
            cvt_hilo(f, Kh[mt], Kl[mt]);
            {
                const float4 a0 = *reinterpret_cast<const float4*>(&lin_w[(size_t)r * ND + ko]);
                const float4 a1 = *reinterpret_cast<const float4*>(&lin_w[(size_t)r * ND + ko + 4]);
                f[0]=a0.x; f[1]=a0.y; f[2]=a0.z; f[3]=a0.w; f[4]=a1.x; f[5]=a1.y; f[6]=a1.z; f[7]=a1.w;
            }
            cvt_hilo(f, Wh[mt], Wl[mt]);
        }
        #pragma unroll
        for (int mt = 0; mt < 2; mt++)
            #pragma unroll
            for (int nt = 0; nt < 2; nt++) {
                f32x16 a = accS[mt][nt];
                a = __builtin_amdgcn_mfma_f32_32x32x16_bf16(Qh[mt], Kh[nt], a, 0, 0, 0);
                a = __builtin_amdgcn_mfma_f32_32x32x16_bf16(Qh[mt], Kl[nt], a, 0, 0, 0);
                a = __builtin_amdgcn_mfma_f32_32x32x16_bf16(Ql[mt], Kh[nt], a, 0, 0, 0);
                accS[mt][nt] = a;
                f32x16 q = accQ[mt][nt];
                q = __builtin_amdgcn_mfma_f32_32x32x16_bf16(Qh[mt], Wh[nt], q, 0, 0, 0);
                q = __builtin_amdgcn_mfma_f32_32x32x16_bf16(Qh[mt], Wl[nt], q, 0, 0, 0);
                q = __builtin_amdgcn_mfma_f32_32x32x16_bf16(Ql[mt], Wh[nt], q, 0, 0, 0);
                accQ[mt][nt] = q;
            }
    }

    {
        float* SPw = SP + w * (64 * 68);
        float* QPw = QP + w * (64 * 68);
        #pragma unroll
        for (int mt = 0; mt < 2; mt++)
            #pragma unroll
            for (int nt = 0; nt < 2; nt++)
                #pragma unroll
                for (int g = 0; g < 16; g++) {
                    const int rg  = 32 * mt + (g & 3) + 8 * (g >> 2) + 4 * h;
                    const int col = 32 * nt + c;
                    SPw[rg * 68 + col] = accS[mt][nt][g];
                    QPw[rg * 68 + col] = accQ[mt][nt][g];
                }
    }
    __syncthreads();

    {
        const int r  = tid >> 2;
        const int cg = (tid & 3) * 16;
        #pragma unroll
        for (int q4 = 0; q4 < 4; ++q4) {
            const int off = r * 68 + cg + q4 * 4;
            float4 s0 = *reinterpret_cast<const float4*>(&SP[off]);
            float4 s1 = *reinterpret_cast<const float4*>(&SP[64 * 68 + off]);
            float4 s2 = *reinterpret_cast<const float4*>(&SP[2 * 64 * 68 + off]);
            float4 s3 = *reinterpret_cast<const float4*>(&SP[3 * 64 * 68 + off]);
            float4 r4;
            r4.x = 8.f * ((s0.x + s1.x) + (s2.x + s3.x));
            r4.y = 8.f * ((s0.y + s1.y) + (s2.y + s3.y));
            r4.z = 8.f * ((s0.z + s1.z) + (s2.z + s3.z));
            r4.w = 8.f * ((s0.w + s1.w) + (s2.w + s3.w));
            *reinterpret_cast<float4*>(&SP[off]) = r4;
            float4 t0 = *reinterpret_cast<const float4*>(&QP[off]);
            float4 t1 = *reinterpret_cast<const float4*>(&QP[64 * 68 + off]);
            float4 t2 = *reinterpret_cast<const float4*>(&QP[2 * 64 * 68 + off]);
            float4 t3 = *reinterpret_cast<const float4*>(&QP[3 * 64 * 68 + off]);
            float4 u4;
            u4.x = (t0.x + t1.x) + (t2.x + t3.x);
            u4.y = (t0.y + t1.y) + (t2.y + t3.y);
            u4.z = (t0.z + t1.z) + (t2.z + t3.z);
            u4.w = (t0.w + t1.w) + (t2.w + t3.w);
            *reinterpret_cast<float4*>(&QP[off]) = u4;
        }
    }
    __syncthreads();

    if (tid < NS) {
        const float* Sr = SP + tid * 68;
        float mx = -INFINITY;
        for (int c2 = 0; c2 < NS; ++c2) mx = fmaxf(mx, Sr[c2]);
        float sum = 0.f;
        for (int c2 = 0; c2 < NS; ++c2) {
            const float e = expf(Sr[c2] - mx);
            Pf[tid * 68 + c2] = e;
            sum += e;
        }
        const float inv = 1.f / sum;
        for (int c2 = 0; c2 < NS; ++c2) Pf[tid * 68 + c2] *= inv;
        for (int c2 = NS; c2 < 64; ++c2) Pf[tid * 68 + c2] = 0.f;
    }
    for (int e = tid; e < NS * NS; e += 256) {
        const int r = e / NS, cc = e - r * NS;
        Ag[b * (NS * NS) + e] = GAMA * (QP[r * 68 + cc] + lin_b[cc]);
    }
    __syncthreads();

    bfrag Ph[2][4], Pl[2][4];
    #pragma unroll
    for (int mt = 0; mt < 2; mt++)
        #pragma unroll
        for (int kt = 0; kt < 4; kt++) {
            float f[8];
            #pragma unroll
            for (int j = 0; j < 8; j++)
                f[j] = Pf[(32 * mt + c) * 68 + kt * 16 + 8 * h + j];
            cvt_hilo(f, Ph[mt][kt], Pl[mt][kt]);
        }

    for (int j3 = 0; j3 < 3; ++j3) {
        const int dbase = (w * 3 + j3) * 64;
        f32x16 accC[2][2];
        #pragma unroll
        for (int mt = 0; mt < 2; mt++)
            #pragma unroll
            for (int nt = 0; nt < 2; nt++)
                #pragma unroll
                for (int g = 0; g < 16; g++) accC[mt][nt][g] = 0.f;

        #pragma unroll
        for (int nt = 0; nt < 2; nt++) {
            const int d = dbase + 32 * nt + c;
            #pragma unroll
            for (int kt = 0; kt < 4; kt++) {
                float f[8];
                #pragma unroll
                for (int j = 0; j < 8; j++) {
                    const int k2 = kt * 16 + 8 * h + j;
                    f[j] = (k2 < NS) ? Vb[(size_t)k2 * ND + d] : 0.f;
                }
                bfrag Bh, Bl;
                cvt_hilo(f, Bh, Bl);
                #pragma unroll
                for (int mt = 0; mt < 2; mt++) {
                    f32x16 a = accC[mt][nt];
                    a = __builtin_amdgcn_mfma_f32_32x32x16_bf16(Ph[mt][kt], Bh, a, 0, 0, 0);
                    a = __builtin_amdgcn_mfma_f32_32x32x16_bf16(Ph[mt][kt], Bl, a, 0, 0, 0);
                    a = __builtin_amdgcn_mfma_f32_32x32x16_bf16(Pl[mt][kt], Bh, a, 0, 0, 0);
                    accC[mt][nt] = a;
                }
            }
        }
        #pragma unroll
        for (int mt = 0; mt < 2; mt++)
            #pragma unroll
            for (int nt = 0; nt < 2; nt++)
                #pragma unroll
                for (int g = 0; g < 16; g++) {
                    const int rg = 32 * mt + (g & 3) + 8 * (g >> 2) + 4 * h;
                    if (rg < NS)
                        ctx_out[((size_t)b * NS + rg) * ND + dbase + 32 * nt + c] = accC[mt][nt][g];
                }
    }
}

// ---------------- Kernel 3: gamma-decay recurrence via MFMA ----------------
// REVERTED to the R13 version (best: ~105us). R17's 2-wave split raised
// occupancy (1.08 -> 2.15 waves/SIMD) but its 45 per-step barriers cost more
// than the TLP gained (+17us). R13's correctness is pure single-wave program
// order: no barriers anywhere. Fat VMEM through LDS layout-transpose.
__global__ __launch_bounds__(64, 1) void recur(
    const float* __restrict__ Ag, const float* __restrict__ ctx,
    float* __restrict__ rec)
{
    const int blk   = blockIdx.x;          // 0..1103
    const int b     = blk / 24;
    const int chunk = blk - b * 24;        // 0..23 -> 32 cols
    const int l     = threadIdx.x;
    const int c     = l & 31;
    const int h     = l >> 5;
    const int d0    = chunk * 32;
    const int srow  = l >> 3;              // 0..7
    const int scol  = (l & 7) * 4;         // 0,4..28

    __shared__ float Sf[64 * 32];
    __shared__ float Cx[64 * 32];

    const float* __restrict__ Ab = Ag + b * (NS * NS);
    bfrag Ah[2][4], Al[2][4];
    #pragma unroll
    for (int mt = 0; mt < 2; mt++) {
        const int row = 32 * mt + c;
        const bool rok = row < NS;
        const float* __restrict__ Arow = Ab + row * NS;
        #pragma unroll
        for (int kt = 0; kt < 4; kt++) {
            FragU uh, ul;
            #pragma unroll
            for (int t = 0; t < 4; t++) {
                const int k0 = 16 * kt + 8 * h + 2 * t;
                const float e = (rok && k0     < NS) ? Arow[k0]     : 0.f;
                const float o = (rok && k0 + 1 < NS) ? Arow[k0 + 1] : 0.f;
                const unsigned ue = __float_as_uint(e), uo = __float_as_uint(o);
                uh.u[t] = (ue >> 16) | (uo & 0xFFFF0000u);
                const float re = e - __uint_as_float(ue & 0xFFFF0000u);
                const float ro = o - __uint_as_float(uo & 0xFFFF0000u);
                ul.u[t] = (__float_as_uint(re) >> 16) | (__float_as_uint(ro) & 0xFFFF0000u);
            }
            Ah[mt][kt] = uh.f; Al[mt][kt] = ul.f;
        }
    }

    {
        const float4 z = make_float4(0.f, 0.f, 0.f, 0.f);
        *reinterpret_cast<float4*>(&Cx[(48 + srow) * 32 + scol]) = z;
        *reinterpret_cast<float4*>(&Cx[(56 + srow) * 32 + scol]) = z;
        *reinterpret_cast<float4*>(&Sf[(48 + srow) * 32 + scol]) = z;
        *reinterpret_cast<float4*>(&Sf[(56 + srow) * 32 + scol]) = z;
    }

    float4 creg[7];
    #pragma unroll
    for (int it = 0; it < 7; ++it) creg[it] = make_float4(0.f, 0.f, 0.f, 0.f);
    {
        const float* __restrict__ src = ctx + d0;
        #pragma unroll
        for (int it = 0; it < 7; ++it) {
            const int r = it * 8 + srow;
            if (r < NS)
                creg[it] = *reinterpret_cast<const float4*>(&src[(size_t)r * ND + scol]);
        }
        float* __restrict__ r0 = rec + (size_t)b * NS * ND + d0;
        #pragma unroll
        for (int it = 0; it < 7; ++it) {
            const int r = it * 8 + srow;
            if (r < NS) {
                *reinterpret_cast<float4*>(&Sf[r * 32 + scol]) = creg[it];
                *reinterpret_cast<float4*>(&r0[(size_t)r * ND + scol]) = creg[it];
            }
        }
    }
    {
        const float* __restrict__ src = ctx + (size_t)NS * ND + d0;
        #pragma unroll
        for (int it = 0; it < 7; ++it) {
            const int r = it * 8 + srow;
            if (r < NS)
                creg[it] = *reinterpret_cast<const float4*>(&src[(size_t)r * ND + scol]);
        }
    }

    for (int i = 1; i < NB; ++i) {
        #pragma unroll
        for (int it = 0; it < 7; ++it) {
            const int r = it * 8 + srow;
            if (r < NS)
                *reinterpret_cast<float4*>(&Cx[r * 32 + scol]) = creg[it];
        }
        if (i + 1 < NB) {
            const float* __restrict__ src = ctx + (size_t)(i + 1) * NS * ND + d0;
            #pragma unroll
            for (int it = 0; it < 7; ++it) {
                const int r = it * 8 + srow;
                if (r < NS)
                    creg[it] = *reinterpret_cast<const float4*>(&src[(size_t)r * ND + scol]);
            }
        }
        f32x16 acc[2];
        #pragma unroll
        for (int mt = 0; mt < 2; mt++)
            #pragma unroll
            for (int g = 0; g < 16; g++) {
                const int rg = 32 * mt + (g & 3) + 8 * (g >> 2) + 4 * h;
                acc[mt][g] = Cx[rg * 32 + c];
            }
        bfrag Bh[4], Bl[4];
        #pragma unroll
        for (int kt = 0; kt < 4; kt++) {
            float f[8];
            #pragma unroll
            for (int j = 0; j < 8; j++)
                f[j] = Sf[(16 * kt + 8 * h + j) * 32 + c];
            FragU uh, ul;
            #pragma unroll
            for (int t = 0; t < 4; t++) {
                const unsigned b0 = __float_as_uint(f[2 * t]);
                const unsigned b1 = __float_as_uint(f[2 * t + 1]);
                uh.u[t] = (b0 >> 16) | (b1 & 0xFFFF0000u);
                const float r0f = f[2 * t]     - __uint_as_float(b0 & 0xFFFF0000u);
                const float r1f = f[2 * t + 1] - __uint_as_float(b1 & 0xFFFF0000u);
                ul.u[t] = (__float_as_uint(r0f) >> 16) | (__float_as_uint(r1f) & 0xFFFF0000u);
            }
            Bh[kt] = uh.f; Bl[kt] = ul.f;
        }
        #pragma unroll
        for (int mt = 0; mt < 2; mt++) {
            f32x16 a = acc[mt];
            #pragma unroll
            for (int kt = 0; kt < 4; kt++)
                a = __builtin_amdgcn_mfma_f32_32x32x16_bf16(Ah[mt][kt], Bh[kt], a, 0, 0, 0);
            #pragma unroll
            for (int kt = 0; kt < 4; kt++)
                a = __builtin_amdgcn_mfma_f32_32x32x16_bf16(Ah[mt][kt], Bl[kt], a, 0, 0, 0);
            #pragma unroll
            for (int kt = 0; kt < 4; kt++)
                a = __builtin_amdgcn_mfma_f32_32x32x16_bf16(Al[mt][kt], Bh[kt], a, 0, 0, 0);
            acc[mt] = a;
        }
        #pragma unroll
        for (int mt = 0; mt < 2; mt++)
            #pragma unroll
            for (int g = 0; g < 16; g++) {
                const int rg = 32 * mt + (g & 3) + 8 * (g >> 2) + 4 * h;
                Sf[rg * 32 + c] = acc[mt][g];
            }
        float* __restrict__ reci = rec + (size_t)(i * NB + b) * NS * ND + d0;
        #pragma unroll
        for (int it = 0; it < 7; ++it) {
            const int r = it * 8 + srow;
            if (r < NS) {
                const float4 v = *reinterpret_cast<const float4*>(&Sf[r * 32 + scol]);
                *reinterpret_cast<float4*>(&reci[(size_t)r * ND + scol]) = v;
            }
        }
    }
}

extern "C" void kernel_launch(void* const* d_in, const int* in_sizes, int n_in,
                              void* d_out, int out_size, void* d_ws, size_t ws_size,
                              hipStream_t stream) {
    const float* text_emb = (const float*)d_in[0];
    const float* emb      = (const float*)d_in[1];
    const float* Wq = (const float*)d_in[2]; const float* bq = (const float*)d_in[3];
    const float* Wk = (const float*)d_in[4]; const float* bk = (const float*)d_in[5];
    const float* Wv = (const float*)d_in[6]; const float* bv = (const float*)d_in[7];
    const float* lw = (const float*)d_in[8]; const float* lb = (const float*)d_in[9];

    float* out = (float*)d_out;
    float* ctx = out;                          // [46,50,768]
    float* rec = out + NB * NS * ND;           // [46,46,50,768]

    float* ws = (float*)d_ws;                  // needs 21.7 MB
    float* Q  = ws;
    float* K  = Q + NB * NS * ND;
    float* V  = K + NB * NS * ND;
    float* Ag = V + NB * NS * ND;              // gamma * Q_trans, [46,50,50]

    qkv_gemm<<<dim3(36, 12, 3), 256, 0, stream>>>(text_emb, emb, Wq, bq, Wk, bk, Wv, bv, Q, K, V);
    attn<<<dim3(NB), 256, 0, stream>>>(Q, K, V, lw, lb, Ag, ctx);
    recur<<<dim3(1104), 64, 0, stream>>>(Ag, ctx, rec);
}